// Round 9
// baseline (109.547 us; speedup 1.0000x reference)
//
#include <hip/hip_runtime.h>
#include <hip/hip_bf16.h>

typedef __attribute__((ext_vector_type(8))) short bf16x8;
typedef __attribute__((ext_vector_type(4))) float f32x4;

#define N_TOT 8192
#define B_IN  4096
#define D_K   256
#define NSPLIT 32   // col splits of 256
#define NPANEL 64   // row panels of 128
#define EXPC 2.8853900817779268f  // 2/ln2

typedef __attribute__((address_space(3))) unsigned int lds_uint;
typedef __attribute__((address_space(1))) const unsigned int glob_uint;

__device__ __forceinline__ unsigned short f2bf(float x) {
  unsigned u = __float_as_uint(x);
  u = (u + 0x7FFFu + ((u >> 16) & 1u)) >> 16;
  return (unsigned short)u;
}
__device__ __forceinline__ float bf2f(unsigned short u) {
  return __uint_as_float(((unsigned)u) << 16);
}

// Normalize each (b,v) row, write bf16 X in anchor order (n = v*B + b), fill labN, histogram cnt.
__global__ void norm_kernel(const float* __restrict__ feat,
                            const int* __restrict__ labels,
                            unsigned short* __restrict__ X,
                            int* __restrict__ labN,
                            int* __restrict__ cnt) {
  int n = blockIdx.x * 4 + (threadIdx.x >> 6);
  int l = threadIdx.x & 63;
  int b = n & (B_IN - 1);
  int v = n >> 12;
  const float4 f = *reinterpret_cast<const float4*>(feat + (size_t)(b * 2 + v) * D_K + l * 4);
  float s = f.x * f.x + f.y * f.y + f.z * f.z + f.w * f.w;
#pragma unroll
  for (int m = 1; m < 64; m <<= 1) s += __shfl_xor(s, m);
  float scale = 1.0f / fmaxf(sqrtf(s), 1e-12f);
  ushort4 o;
  o.x = f2bf(f.x * scale);
  o.y = f2bf(f.y * scale);
  o.z = f2bf(f.z * scale);
  o.w = f2bf(f.w * scale);
  *reinterpret_cast<ushort4*>(X + (size_t)n * D_K + l * 4) = o;
  if (l == 0) {
    int lb = labels[b];
    labN[n] = lb;
    if (n < B_IN) atomicAdd(&cnt[lb], 1);  // integer atomic: deterministic
  }
}

// Class-sum vectors: G[c] = sum of normalized rows (both views) with label c. 1000 blocks x 64 thr.
__global__ void classsum_kernel(const unsigned short* __restrict__ X,
                                const int* __restrict__ labels,
                                float* __restrict__ G) {
  const int c = blockIdx.x;
  const int l = threadIdx.x;
  float a0 = 0.f, a1 = 0.f, a2 = 0.f, a3 = 0.f;
  for (int it = 0; it < B_IN / 64; ++it) {
    unsigned long long m = __ballot(labels[it * 64 + l] == c);
    while (m) {
      int bit = __ffsll((long long)m) - 1;
      m &= m - 1;
      int b = it * 64 + bit;
      ushort4 r0 = *reinterpret_cast<const ushort4*>(X + (size_t)b * D_K + l * 4);
      ushort4 r1 = *reinterpret_cast<const ushort4*>(X + (size_t)(b + B_IN) * D_K + l * 4);
      a0 += bf2f(r0.x) + bf2f(r1.x);
      a1 += bf2f(r0.y) + bf2f(r1.y);
      a2 += bf2f(r0.z) + bf2f(r1.z);
      a3 += bf2f(r0.w) + bf2f(r1.w);
    }
  }
  float4 o = {a0, a1, a2, a3};
  *reinterpret_cast<float4*>(G + (size_t)c * D_K + l * 4) = o;
}

// Main: 2048 blocks = 64 row-panels (128 rows) x 32 col-splits (256 cols).
// 256 threads = 4 waves; wave w owns rows [rbase + w*32, +32): A in 64 VGPRs.
// Cols streamed as 8 tiles of 32 via global_load_lds into 3x16KB LDS rings.
// Raw s_barrier + counted vmcnt(4): loads stay in flight across barriers.
// S-only epilogue (P computed via class sums elsewhere).
__global__ __launch_bounds__(256, 3) void main_kernel(const unsigned short* __restrict__ X,
                                                      float* __restrict__ SpA) {
  __shared__ __align__(16) char Bs[3][16384];
  const int tid = threadIdx.x;
  const int l = tid & 63, w = tid >> 6;
  const int lm = l & 15, lh = l >> 4;
  const int panel = blockIdx.x >> 5;  // 64 panels of 128 rows
  const int split = blockIdx.x & 31;  // 32 splits of 256 cols
  const int rbase = panel * 128;
  const int cbase = split * 256;
  const int wrow = rbase + w * 32;
  const int4* Xg = reinterpret_cast<const int4*>(X);  // 32 int4 per row

  // per-thread staging source pointers (tile 0); source pre-swizzled slot e -> e^(row&7)
  const int4* gbase[4];
#pragma unroll
  for (int i = 0; i < 4; ++i) {
    int c = i * 256 + tid;
    int row = c >> 5;
    int c16s = (c & 31) ^ (row & 7);
    gbase[i] = Xg + (size_t)(cbase + row) * 32 + c16s;
  }

  // stage tile 0 into Bs[0]
#pragma unroll
  for (int i = 0; i < 4; ++i) {
    char* s = &Bs[0][0] + (size_t)(i * 256 + (w << 6)) * 16;  // wave-uniform base
    __builtin_amdgcn_global_load_lds((glob_uint*)gbase[i], (lds_uint*)s, 16, 0, 0);
  }

  // A fragments: rows wrow + fi*16 + lm, elems kk*32 + lh*8 .. +7
  bf16x8 a[2][8];
#pragma unroll
  for (int fi = 0; fi < 2; ++fi)
#pragma unroll
    for (int kk = 0; kk < 8; ++kk)
      a[fi][kk] = *reinterpret_cast<const bf16x8*>(
          X + (size_t)(wrow + fi * 16 + lm) * D_K + kk * 32 + lh * 8);

  float S[2][4] = {};

#pragma unroll
  for (int jt = 0; jt < 8; ++jt) {
    if (jt < 7) {
      // stage jt+1 into ring buffer (its readers ran at jt-2, two barriers back)
      char* buf = &Bs[(jt + 1) % 3][0];
#pragma unroll
      for (int i = 0; i < 4; ++i) {
        const int4* g = gbase[i] + (size_t)(jt + 1) * 1024;
        char* s = buf + (size_t)(i * 256 + (w << 6)) * 16;
        __builtin_amdgcn_global_load_lds((glob_uint*)g, (lds_uint*)s, 16, 0, 0);
      }
      asm volatile("s_waitcnt vmcnt(4)" ::: "memory");  // tile jt landed; jt+1 in flight
    } else {
      asm volatile("s_waitcnt vmcnt(0)" ::: "memory");
    }
    __builtin_amdgcn_s_barrier();
    __builtin_amdgcn_sched_barrier(0);

    const char* bufc = &Bs[jt % 3][0];
    f32x4 acc[2][2];
#pragma unroll
    for (int fi = 0; fi < 2; ++fi) {
      acc[fi][0] = (f32x4){0.f, 0.f, 0.f, 0.f};
      acc[fi][1] = (f32x4){0.f, 0.f, 0.f, 0.f};
    }
    const int ba0 = lm * 512, sw0 = (lm & 7) << 4;
    const int ba1 = (lm + 16) * 512;  // same low-3 bits -> same swizzle
#pragma unroll
    for (int kk = 0; kk < 8; ++kk) {
      int ko = (kk * 64 + lh * 16) ^ sw0;
      bf16x8 b0 = *reinterpret_cast<const bf16x8*>(bufc + ba0 + ko);
      bf16x8 b1 = *reinterpret_cast<const bf16x8*>(bufc + ba1 + ko);
#pragma unroll
      for (int fi = 0; fi < 2; ++fi) {
        acc[fi][0] = __builtin_amdgcn_mfma_f32_16x16x32_bf16(a[fi][kk], b0, acc[fi][0], 0, 0, 0);
        acc[fi][1] = __builtin_amdgcn_mfma_f32_16x16x32_bf16(a[fi][kk], b1, acc[fi][1], 0, 0, 0);
      }
    }
    // epilogue: S += exp(2v-2) = exp2(C*v - C) over ALL cols (self removed in reduce)
#pragma unroll
    for (int fi = 0; fi < 2; ++fi)
#pragma unroll
      for (int fj = 0; fj < 2; ++fj)
#pragma unroll
        for (int r = 0; r < 4; ++r)
          S[fi][r] += exp2f(fmaf(acc[fi][fj][r], EXPC, -EXPC));
  }

  // row credit: reduce across the 16 lm lanes; one writer per (split,row)
#pragma unroll
  for (int fi = 0; fi < 2; ++fi)
#pragma unroll
    for (int r = 0; r < 4; ++r) {
      float s = S[fi][r];
#pragma unroll
      for (int m = 1; m < 16; m <<= 1) s += __shfl_xor(s, m);
      if (lm == 0) {
        int row = wrow + fi * 16 + lh * 4 + r;
        SpA[split * N_TOT + row] = s;
      }
    }
}

// Per-anchor loss: one wave per n (16 n's per wave). 128 blocks x 256 thr.
__global__ void reduceA_kernel(const float* __restrict__ Sp,
                               const unsigned short* __restrict__ X,
                               const float* __restrict__ G,
                               const int* __restrict__ labN,
                               const int* __restrict__ cnt,
                               float* __restrict__ tmp) {
  const int w = threadIdx.x >> 6, l = threadIdx.x & 63;
  const int gw = blockIdx.x * 4 + w;  // 0..511
  for (int k = 0; k < 16; ++k) {
    int n = gw * 16 + k;
    int lab = labN[n];
    ushort4 xr = *reinterpret_cast<const ushort4*>(X + (size_t)n * D_K + l * 4);
    float4 gr = *reinterpret_cast<const float4*>(G + (size_t)lab * D_K + l * 4);
    float dp = bf2f(xr.x) * gr.x + bf2f(xr.y) * gr.y + bf2f(xr.z) * gr.z + bf2f(xr.w) * gr.w;
    float sl = (l < NSPLIT) ? Sp[l * N_TOT + n] : 0.f;
#pragma unroll
    for (int m = 1; m < 64; m <<= 1) {
      dp += __shfl_xor(dp, m);
      sl += __shfl_xor(sl, m);
    }
    if (l == 0) {
      float S = sl - 1.0f;            // remove self exp term (exp(2*selfdot-2) ~= 1)
      float P = 2.0f * dp - 2.0f;     // G includes self; remove self logit (~= 2)
      float np = (float)(2 * cnt[lab] - 1);
      tmp[n] = logf(S) + 2.0f - P / np;
    }
  }
}

__global__ void reduceB_kernel(const float* __restrict__ tmp, float* __restrict__ out) {
  __shared__ float red[4];
  int tid = threadIdx.x;
  float acc = 0.f;
  for (int i = tid; i < N_TOT; i += 256) acc += tmp[i];
#pragma unroll
  for (int m = 1; m < 64; m <<= 1) acc += __shfl_xor(acc, m);
  if ((tid & 63) == 0) red[tid >> 6] = acc;
  __syncthreads();
  if (tid == 0) out[0] = (red[0] + red[1] + red[2] + red[3]) * (1.0f / (float)N_TOT);
}

extern "C" void kernel_launch(void* const* d_in, const int* in_sizes, int n_in,
                              void* d_out, int out_size, void* d_ws, size_t ws_size,
                              hipStream_t stream) {
  const float* feat = (const float*)d_in[0];
  const int* labels = (const int*)d_in[1];
  char* ws = (char*)d_ws;
  unsigned short* X = (unsigned short*)ws;   // 4 MB
  int* labN = (int*)(ws + 4194304);          // 32 KB
  int* cnt = (int*)(ws + 4227072);           // 4 KB
  float* Sp = (float*)(ws + 4231168);        // 32*8192*4 = 1 MB
  float* G = (float*)(ws + 5279744);         // 1000*256*4 = 1000 KB
  float* tmp = (float*)(ws + 6303744);       // 32 KB
  float* out = (float*)d_out;

  hipMemsetAsync(cnt, 0, 4096, stream);
  norm_kernel<<<2048, 256, 0, stream>>>(feat, labels, X, labN, cnt);
  classsum_kernel<<<1000, 64, 0, stream>>>(X, labels, G);
  main_kernel<<<NPANEL * NSPLIT, 256, 0, stream>>>(X, Sp);
  reduceA_kernel<<<128, 256, 0, stream>>>(Sp, X, G, labN, cnt, tmp);
  reduceB_kernel<<<1, 256, 0, stream>>>(tmp, out);
}